// Round 12
// baseline (57.642 us; speedup 1.0000x reference)
//
#include <hip/hip_runtime.h>
#include <hip/hip_bf16.h>
#include <math.h>

#define D 32
#define CAP 33      // per-class LDS list capacity (33 also pads banks); fallback beyond
#define PBT 256     // k_pb threads = classes per block (4 waves)
#define SBT 512     // k_score threads (8 waves)
#define SSM 16      // samples per k_score block

typedef __attribute__((ext_vector_type(8))) short short8v;
typedef __attribute__((ext_vector_type(4))) float float4v;

static __device__ __forceinline__ unsigned short f2bf(float f) {
    union { __hip_bfloat16 h; unsigned short u; } cv;
    cv.h = __float2bfloat16(f);
    return cv.u;
}

// one sequential EMA step, fully per-lane (no cross-lane ops, all static indexing)
static __device__ __forceinline__ void ema_step(float p[D], const float* __restrict__ x, int idx) {
    float r0[D];
#pragma unroll
    for (int j = 0; j < D / 4; ++j) {
        float4 v = ((const float4*)(x + (size_t)idx * D))[j];
        r0[4*j] = v.x; r0[4*j+1] = v.y; r0[4*j+2] = v.z; r0[4*j+3] = v.w;
    }
    float s0 = 0.f, s1 = 0.f, s2 = 0.f, s3 = 0.f;
#pragma unroll
    for (int j = 0; j < D / 4; ++j) {
        s0 = fmaf(r0[4*j],   r0[4*j],   s0);
        s1 = fmaf(r0[4*j+1], r0[4*j+1], s1);
        s2 = fmaf(r0[4*j+2], r0[4*j+2], s2);
        s3 = fmaf(r0[4*j+3], r0[4*j+3], s3);
    }
    float inv = 1.0f / fmaxf(sqrtf((s0 + s1) + (s2 + s3)), 1e-12f);  // sample norm (eps 1e-12)
    float c05 = 0.05f * inv;
#pragma unroll
    for (int j = 0; j < D; ++j) p[j] = fmaf(c05, r0[j], 0.95f * p[j]);
    float q0 = 0.f, q1 = 0.f, q2 = 0.f, q3 = 0.f;
#pragma unroll
    for (int j = 0; j < D / 4; ++j) {
        q0 = fmaf(p[4*j],   p[4*j],   q0);
        q1 = fmaf(p[4*j+1], p[4*j+1], q1);
        q2 = fmaf(p[4*j+2], p[4*j+2], q2);
        q3 = fmaf(p[4*j+3], p[4*j+3], q3);
    }
    float inv2 = 1.0f / fmaxf(sqrtf((q0 + q1) + (q2 + q3)), 1e-12f); // proto renorm (eps 1e-12)
#pragma unroll
    for (int j = 0; j < D; ++j) p[j] *= inv2;
}

// ---- K1: LDS bucket + per-LANE (class) sequential EMA chain -> qb, w ----
// 8 blocks x 256 threads; lane tid owns class b*256+tid. Chain is pure VALU:
// no cross-lane shuffles (the old 5-shuffle-per-step dependent DS chain was the cost).
__global__ void __launch_bounds__(PBT)
k_pb(const float* __restrict__ x, const int* __restrict__ tgt,
     const float* __restrict__ p_in, const float* __restrict__ kw,
     unsigned short* __restrict__ qb, float* __restrict__ w,
     int N, int C, float dval) {
    __shared__ int lcnt[PBT];
    __shared__ int llist[PBT][CAP];    // (tid*33+k) -> bank (tid+k)%32: conflict-free-ish
    int tid = threadIdx.x, b = blockIdx.x;
    int c0 = b * PBT;
    int c = c0 + tid;

    // Phase A: scan all targets, unordered scatter into per-class LDS lists
    lcnt[tid] = 0;
    __syncthreads();
#pragma unroll 4
    for (int i = tid; i < N; i += PBT) {       // 64 coalesced iterations
        int t = tgt[i];
        int r = t - c0;
        if ((unsigned)r < (unsigned)PBT) {
            int pos = atomicAdd(&lcnt[r], 1);  // LDS atomic
            if (pos < CAP) llist[r][pos] = i;
        }
    }
    __syncthreads();

    int cnt = lcnt[tid];

    // prototype row into registers
    float p[D];
#pragma unroll
    for (int j = 0; j < D / 4; ++j) {
        float4 v = ((const float4*)(p_in + (size_t)c * D))[j];
        p[4*j] = v.x; p[4*j+1] = v.y; p[4*j+2] = v.z; p[4*j+3] = v.w;
    }

    if (cnt <= CAP) {
        // Phase B: ascending-index order via per-step selection-min over own LDS list
        int last = -1;
        for (int step = 0; step < cnt; ++step) {
            int best = 0x7fffffff;
            for (int k = 0; k < cnt; ++k) {
                int v = llist[tid][k];
                if (v > last && v < best) best = v;
            }
            last = best;
            ema_step(p, x, best);
        }
    } else {
        // exact fallback (statistically never at N/C=8): ascending rescan of tgt
        for (int i = 0; i < N; ++i)
            if (tgt[i] == c) ema_step(p, x, i);
    }

    // finalize: cosine-normalize (eps 1e-8), fold kappa, write qb row + w
    float q0 = 0.f, q1 = 0.f, q2 = 0.f, q3 = 0.f;
#pragma unroll
    for (int j = 0; j < D / 4; ++j) {
        q0 = fmaf(p[4*j],   p[4*j],   q0);
        q1 = fmaf(p[4*j+1], p[4*j+1], q1);
        q2 = fmaf(p[4*j+2], p[4*j+2], q2);
        q3 = fmaf(p[4*j+3], p[4*j+3], q3);
    }
    float pninv = 1.0f / fmaxf(sqrtf((q0 + q1) + (q2 + q3)), 1e-8f);
    float kap = fmaxf(kw[c], 0.0f);
    float scale = kap * pninv;
#pragma unroll
    for (int j = 0; j < D / 2; ++j) {
        unsigned int lo = f2bf(scale * p[2*j]);
        unsigned int hi = f2bf(scale * p[2*j+1]);
        ((unsigned int*)(qb + (size_t)c * D))[j] = lo | (hi << 16);
    }
    {
        // log C_d(kap), cancellation-free rearrangement
        float nu = 0.5f * dval - 1.0f;
        float z  = kap / nu, z2 = z * z;
        float sq = sqrtf(1.0f + z2);
        float t  = 1.0f / sq;
        float u1 = (3.0f * t - 5.0f * t * t * t) * (1.0f / 24.0f);
        float lw = dval * (-0.918938533204672742f)
                 + nu * (logf(nu) + log1pf(sq) - sq)
                 + 0.5f * logf(6.2831853071795864f * nu)
                 + 0.25f * log1pf(z2)
                 - log1pf(u1 / nu);
        w[c] = __expf(lw);
    }
}

// ---- K2: per-block full-row MFMA + exp rowsum + target-logit capture + NLL ----
// (unchanged from round 11) 1024 blocks x 8 waves; block owns 16 samples.
__global__ void __launch_bounds__(SBT)
k_score(const float* __restrict__ x, const int* __restrict__ tgt,
        const unsigned short* __restrict__ qb, const float* __restrict__ w,
        float* __restrict__ part, int N, int C) {
    __shared__ float Sl[8][SSM];
    __shared__ float Lt[SSM];
    int tid = threadIdx.x, b = blockIdx.x;
    int lane = tid & 63, wv = tid >> 6;
    int m = lane & 15, kg = lane >> 4, k0 = kg * 8;
    int s0 = b * SSM;

    short8v a0;
    {
        const float4* px = (const float4*)(x + (size_t)(s0 + m) * D + k0);
        float4 u0 = px[0], u1 = px[1];
        float ss = u0.x*u0.x + u0.y*u0.y + u0.z*u0.z + u0.w*u0.w
                 + u1.x*u1.x + u1.y*u1.y + u1.z*u1.z + u1.w*u1.w;
        ss += __shfl_xor(ss, 16); ss += __shfl_xor(ss, 32);
        float inv = 1.0f / fmaxf(sqrtf(ss), 1e-8f);
        a0[0] = (short)f2bf(u0.x*inv); a0[1] = (short)f2bf(u0.y*inv);
        a0[2] = (short)f2bf(u0.z*inv); a0[3] = (short)f2bf(u0.w*inv);
        a0[4] = (short)f2bf(u1.x*inv); a0[5] = (short)f2bf(u1.y*inv);
        a0[6] = (short)f2bf(u1.z*inv); a0[7] = (short)f2bf(u1.w*inv);
    }

    int tr0[4];
#pragma unroll
    for (int r = 0; r < 4; ++r) tr0[r] = tgt[s0 + kg * 4 + r];

    float4v z = {0.f, 0.f, 0.f, 0.f};
    float4v sa0 = z;
    int ntiles = C >> 7;
    for (int jt = 0; jt < ntiles; ++jt) {
        int c0 = (wv * ntiles + jt) * 16;
        short8v bfrag = *(const short8v*)(qb + (size_t)(c0 + m) * D + k0);
        float wl = w[c0 + m];
        float4v acc0 = __builtin_amdgcn_mfma_f32_16x16x32_bf16(a0, bfrag, z, 0, 0, 0);
#pragma unroll
        for (int r = 0; r < 4; ++r) {
            if (c0 + m == tr0[r]) Lt[kg * 4 + r] = acc0[r];
            sa0[r] = fmaf(wl, __expf(acc0[r]), sa0[r]);
        }
    }
#pragma unroll
    for (int off = 1; off < 16; off <<= 1) {
#pragma unroll
        for (int r = 0; r < 4; ++r) sa0[r] += __shfl_xor(sa0[r], off);
    }
    if (m == 0) {
#pragma unroll
        for (int r = 0; r < 4; ++r) Sl[wv][kg * 4 + r] = sa0[r];
    }
    __syncthreads();

    if (wv == 0) {
        float val = 0.f;
        if (lane < SSM) {
            int s = lane;
            float S = ((Sl[0][s] + Sl[1][s]) + (Sl[2][s] + Sl[3][s]))
                    + ((Sl[4][s] + Sl[5][s]) + (Sl[6][s] + Sl[7][s]));
            int t = tgt[s0 + s];
            val = logf(w[t] * __expf(Lt[s]) / S + 1e-6f);
        }
        val += __shfl_xor(val, 32); val += __shfl_xor(val, 16); val += __shfl_xor(val, 8);
        val += __shfl_xor(val, 4);  val += __shfl_xor(val, 2);  val += __shfl_xor(val, 1);
        if (lane == 0) part[b] = val;
    }
}

// ---- K3: deterministic fixed-order final reduce (1 block, 1024 partials) ----
__global__ void k_out(const float* __restrict__ part, float* __restrict__ out,
                      int N, int nblk) {
    __shared__ float red[8];
    int tid = threadIdx.x, lane = tid & 63, wv = tid >> 6;
    float v = 0.f;
    if (tid < nblk)       v += part[tid];
    if (tid + 512 < nblk) v += part[tid + 512];
    v += __shfl_xor(v, 32); v += __shfl_xor(v, 16); v += __shfl_xor(v, 8);
    v += __shfl_xor(v, 4);  v += __shfl_xor(v, 2);  v += __shfl_xor(v, 1);
    if (lane == 0) red[wv] = v;
    __syncthreads();
    if (tid == 0)
        out[0] = -(((red[0] + red[1]) + (red[2] + red[3]))
                 + ((red[4] + red[5]) + (red[6] + red[7]))) / (float)N;
}

extern "C" void kernel_launch(void* const* d_in, const int* in_sizes, int n_in,
                              void* d_out, int out_size, void* d_ws, size_t ws_size,
                              hipStream_t stream) {
    const float* x    = (const float*)d_in[0];   // [N, D]
    const float* kw   = (const float*)d_in[1];   // [C]
    const float* p_in = (const float*)d_in[2];   // [C, D]
    const int*   tgt  = (const int*)d_in[3];     // [N]
    int C = in_sizes[1];
    int N = in_sizes[3];
    float dval = (float)(in_sizes[2] / C);       // == 32
    int nblk = N / SSM;                           // 1024 score blocks

    // ws layout: qb | w | part
    unsigned short* qb = (unsigned short*)d_ws;            // C*D bf16
    float* w    = (float*)(qb + (size_t)C * D);            // C f32
    float* part = w + C;                                   // nblk f32
    (void)n_in; (void)out_size; (void)ws_size;

    // node 1: LDS-bucket + per-lane EMA chains -> qb, w
    k_pb<<<C / PBT, PBT, 0, stream>>>(x, tgt, p_in, kw, qb, w, N, C, dval);
    // node 2: full-row score + NLL partials
    k_score<<<nblk, SBT, 0, stream>>>(x, tgt, qb, w, part, N, C);
    // node 3: final reduce
    k_out<<<1, 512, 0, stream>>>(part, (float*)d_out, N, nblk);
}

// Round 13
// 51.194 us; speedup vs baseline: 1.1260x; 1.1260x over previous
//
#include <hip/hip_runtime.h>
#include <hip/hip_bf16.h>
#include <math.h>

#define D 32
#define CAP 32      // per-class list capacity (exact fallback beyond; Poisson(8) max ~22)
#define SBT 512     // k_score threads (8 waves)
#define SSM 16      // samples per k_score block

typedef __attribute__((ext_vector_type(8))) short short8v;
typedef __attribute__((ext_vector_type(4))) float float4v;

static __device__ __forceinline__ unsigned short f2bf(float f) {
    union { __hip_bfloat16 h; unsigned short u; } cv;
    cv.h = __float2bfloat16(f);
    return cv.u;
}
static __device__ __forceinline__ float bflo(unsigned int u) {
    union { float f; unsigned int i; } c; c.i = u << 16; return c.f;
}
static __device__ __forceinline__ float bfhi(unsigned int u) {
    union { float f; unsigned int i; } c; c.i = u & 0xffff0000u; return c.f;
}

// EMA-merge one uint4 (8 bf16) into two float4 proto chunks
#define EMA_U4(r, pa, pb)                                   \
    pa.x = fmaf(0.05f, bflo(r.x), 0.95f * pa.x);            \
    pa.y = fmaf(0.05f, bfhi(r.x), 0.95f * pa.y);            \
    pa.z = fmaf(0.05f, bflo(r.y), 0.95f * pa.z);            \
    pa.w = fmaf(0.05f, bfhi(r.y), 0.95f * pa.w);            \
    pb.x = fmaf(0.05f, bflo(r.z), 0.95f * pb.x);            \
    pb.y = fmaf(0.05f, bfhi(r.z), 0.95f * pb.y);            \
    pb.z = fmaf(0.05f, bflo(r.w), 0.95f * pb.z);            \
    pb.w = fmaf(0.05f, bfhi(r.w), 0.95f * pb.w);

#define SQ4(v) fmaf(v.x, v.x, fmaf(v.y, v.y, fmaf(v.z, v.z, v.w * v.w)))
#define SC4(v, s) v.x *= s; v.y *= s; v.z *= s; v.w *= s;

// proto renorm (eps 1e-12), per-lane, 4 accumulator chains
#define RENORM()                                                            \
    {                                                                       \
        float q0 = SQ4(p0) + SQ4(p4), q1 = SQ4(p1) + SQ4(p5);               \
        float q2 = SQ4(p2) + SQ4(p6), q3 = SQ4(p3) + SQ4(p7);               \
        float inv2 = 1.0f / fmaxf(sqrtf((q0 + q1) + (q2 + q3)), 1e-12f);    \
        SC4(p0, inv2) SC4(p1, inv2) SC4(p2, inv2) SC4(p3, inv2)             \
        SC4(p4, inv2) SC4(p5, inv2) SC4(p6, inv2) SC4(p7, inv2)             \
    }

// ---- K1: normalize samples (eps 1e-12) -> bf16 xnb, + bucket scatter ----
__global__ void k_norm(const float* __restrict__ x, const int* __restrict__ tgt,
                       unsigned short* __restrict__ xnb,
                       int* __restrict__ cnt, int* __restrict__ list2d, int N) {
    int g = blockIdx.x * blockDim.x + threadIdx.x;   // N*8 threads, 8 lanes/sample
    int i = g >> 3, q = g & 7;
    if (i >= N) return;
    float4 v = ((const float4*)(x + (size_t)i * D))[q];
    float ss = v.x*v.x + v.y*v.y + v.z*v.z + v.w*v.w;
    ss += __shfl_xor(ss, 1); ss += __shfl_xor(ss, 2); ss += __shfl_xor(ss, 4);
    float inv = 1.0f / fmaxf(sqrtf(ss), 1e-12f);
    ushort4 ob;
    ob.x = f2bf(v.x * inv); ob.y = f2bf(v.y * inv);
    ob.z = f2bf(v.z * inv); ob.w = f2bf(v.w * inv);
    ((ushort4*)(xnb + (size_t)i * D))[q] = ob;
    if (q == 0) {
        int t = tgt[i];
        int pos = atomicAdd(&cnt[t], 1);
        if (pos < CAP) list2d[t * CAP + pos] = i;   // unordered; chain re-orders
    }
}

// ---- K2: per-LANE sequential EMA chain, register-resident, shuffle-free ----
// 32 blocks x 64 lanes; lane owns class c. Depth-2 row prefetch hides L2 latency.
__global__ void k_chain(const unsigned short* __restrict__ xnb, const int* __restrict__ tgt,
                        const int* __restrict__ list2d, const int* __restrict__ cnt,
                        const float* __restrict__ p_in, const float* __restrict__ kw,
                        unsigned short* __restrict__ qb, float* __restrict__ w,
                        int N, int C, float dval) {
    int c = blockIdx.x * 64 + threadIdx.x;
    if (c >= C) return;

    const float4* pr = (const float4*)(p_in + (size_t)c * D);
    float4 p0 = pr[0], p1 = pr[1], p2 = pr[2], p3 = pr[3];
    float4 p4 = pr[4], p5 = pr[5], p6 = pr[6], p7 = pr[7];

    int n = cnt[c];

    if (n <= CAP) {
        int li[CAP];
#pragma unroll
        for (int k = 0; k < CAP; ++k)
            li[k] = (k < n) ? list2d[c * CAP + k] : 0x7fffffff;

        int last = 0x7fffffff;
#pragma unroll
        for (int k = 0; k < CAP; ++k) last = min(last, li[k]);   // first index

        uint4 r0, r1, r2, r3;
        if (n > 0) {
            const uint4* row = (const uint4*)(xnb + (size_t)last * D);
            r0 = row[0]; r1 = row[1]; r2 = row[2]; r3 = row[3];
        }
        for (int step = 0; step < n; ++step) {
            // successor of 'last' (register scan, no mutation, no shuffles)
            int nb = 0x7fffffff;
#pragma unroll
            for (int k = 0; k < CAP; ++k) {
                int vv = li[k];
                if (vv > last && vv < nb) nb = vv;
            }
            uint4 t0, t1, t2, t3;
            if (step + 1 < n) {          // prefetch successor row (exec-masked)
                const uint4* row = (const uint4*)(xnb + (size_t)nb * D);
                t0 = row[0]; t1 = row[1]; t2 = row[2]; t3 = row[3];
            }
            EMA_U4(r0, p0, p1) EMA_U4(r1, p2, p3)
            EMA_U4(r2, p4, p5) EMA_U4(r3, p6, p7)
            RENORM()
            r0 = t0; r1 = t1; r2 = t2; r3 = t3;
            last = nb;
        }
    } else {
        // exact fallback (statistically never at N/C=8): ascending scan of tgt
        for (int i = 0; i < N; ++i) {
            if (tgt[i] == c) {
                const uint4* row = (const uint4*)(xnb + (size_t)i * D);
                uint4 a0 = row[0], a1 = row[1], a2 = row[2], a3 = row[3];
                EMA_U4(a0, p0, p1) EMA_U4(a1, p2, p3)
                EMA_U4(a2, p4, p5) EMA_U4(a3, p6, p7)
                RENORM()
            }
        }
    }

    // finalize: cosine-normalize (eps 1e-8), fold kappa, write qb + w
    float q0 = SQ4(p0) + SQ4(p4), q1 = SQ4(p1) + SQ4(p5);
    float q2 = SQ4(p2) + SQ4(p6), q3 = SQ4(p3) + SQ4(p7);
    float pninv = 1.0f / fmaxf(sqrtf((q0 + q1) + (q2 + q3)), 1e-8f);
    float kap = fmaxf(kw[c], 0.0f);
    float sc = kap * pninv;
    unsigned int* qo = (unsigned int*)(qb + (size_t)c * D);
#define PACK2(a, b) (f2bf(sc * (a)) | ((unsigned int)f2bf(sc * (b)) << 16))
    qo[0]  = PACK2(p0.x, p0.y); qo[1]  = PACK2(p0.z, p0.w);
    qo[2]  = PACK2(p1.x, p1.y); qo[3]  = PACK2(p1.z, p1.w);
    qo[4]  = PACK2(p2.x, p2.y); qo[5]  = PACK2(p2.z, p2.w);
    qo[6]  = PACK2(p3.x, p3.y); qo[7]  = PACK2(p3.z, p3.w);
    qo[8]  = PACK2(p4.x, p4.y); qo[9]  = PACK2(p4.z, p4.w);
    qo[10] = PACK2(p5.x, p5.y); qo[11] = PACK2(p5.z, p5.w);
    qo[12] = PACK2(p6.x, p6.y); qo[13] = PACK2(p6.z, p6.w);
    qo[14] = PACK2(p7.x, p7.y); qo[15] = PACK2(p7.z, p7.w);
#undef PACK2
    {
        // log C_d(kap), cancellation-free rearrangement
        float nu = 0.5f * dval - 1.0f;
        float z  = kap / nu, z2 = z * z;
        float sq = sqrtf(1.0f + z2);
        float t  = 1.0f / sq;
        float u1 = (3.0f * t - 5.0f * t * t * t) * (1.0f / 24.0f);
        float lw = dval * (-0.918938533204672742f)
                 + nu * (logf(nu) + log1pf(sq) - sq)
                 + 0.5f * logf(6.2831853071795864f * nu)
                 + 0.25f * log1pf(z2)
                 - log1pf(u1 / nu);
        w[c] = __expf(lw);
    }
}

// ---- K3: per-block full-row MFMA + exp rowsum + target-logit capture + NLL ----
// (unchanged from round 11) 1024 blocks x 8 waves; block owns 16 samples.
__global__ void __launch_bounds__(SBT)
k_score(const float* __restrict__ x, const int* __restrict__ tgt,
        const unsigned short* __restrict__ qb, const float* __restrict__ w,
        float* __restrict__ part, int N, int C) {
    __shared__ float Sl[8][SSM];
    __shared__ float Lt[SSM];
    int tid = threadIdx.x, b = blockIdx.x;
    int lane = tid & 63, wv = tid >> 6;
    int m = lane & 15, kg = lane >> 4, k0 = kg * 8;
    int s0 = b * SSM;

    short8v a0;
    {
        const float4* px = (const float4*)(x + (size_t)(s0 + m) * D + k0);
        float4 u0 = px[0], u1 = px[1];
        float ss = u0.x*u0.x + u0.y*u0.y + u0.z*u0.z + u0.w*u0.w
                 + u1.x*u1.x + u1.y*u1.y + u1.z*u1.z + u1.w*u1.w;
        ss += __shfl_xor(ss, 16); ss += __shfl_xor(ss, 32);
        float inv = 1.0f / fmaxf(sqrtf(ss), 1e-8f);
        a0[0] = (short)f2bf(u0.x*inv); a0[1] = (short)f2bf(u0.y*inv);
        a0[2] = (short)f2bf(u0.z*inv); a0[3] = (short)f2bf(u0.w*inv);
        a0[4] = (short)f2bf(u1.x*inv); a0[5] = (short)f2bf(u1.y*inv);
        a0[6] = (short)f2bf(u1.z*inv); a0[7] = (short)f2bf(u1.w*inv);
    }

    int tr0[4];
#pragma unroll
    for (int r = 0; r < 4; ++r) tr0[r] = tgt[s0 + kg * 4 + r];

    float4v z = {0.f, 0.f, 0.f, 0.f};
    float4v sa0 = z;
    int ntiles = C >> 7;
    for (int jt = 0; jt < ntiles; ++jt) {
        int c0 = (wv * ntiles + jt) * 16;
        short8v bfrag = *(const short8v*)(qb + (size_t)(c0 + m) * D + k0);
        float wl = w[c0 + m];
        float4v acc0 = __builtin_amdgcn_mfma_f32_16x16x32_bf16(a0, bfrag, z, 0, 0, 0);
#pragma unroll
        for (int r = 0; r < 4; ++r) {
            if (c0 + m == tr0[r]) Lt[kg * 4 + r] = acc0[r];
            sa0[r] = fmaf(wl, __expf(acc0[r]), sa0[r]);
        }
    }
#pragma unroll
    for (int off = 1; off < 16; off <<= 1) {
#pragma unroll
        for (int r = 0; r < 4; ++r) sa0[r] += __shfl_xor(sa0[r], off);
    }
    if (m == 0) {
#pragma unroll
        for (int r = 0; r < 4; ++r) Sl[wv][kg * 4 + r] = sa0[r];
    }
    __syncthreads();

    if (wv == 0) {
        float val = 0.f;
        if (lane < SSM) {
            int s = lane;
            float S = ((Sl[0][s] + Sl[1][s]) + (Sl[2][s] + Sl[3][s]))
                    + ((Sl[4][s] + Sl[5][s]) + (Sl[6][s] + Sl[7][s]));
            int t = tgt[s0 + s];
            val = logf(w[t] * __expf(Lt[s]) / S + 1e-6f);
        }
        val += __shfl_xor(val, 32); val += __shfl_xor(val, 16); val += __shfl_xor(val, 8);
        val += __shfl_xor(val, 4);  val += __shfl_xor(val, 2);  val += __shfl_xor(val, 1);
        if (lane == 0) part[b] = val;
    }
}

// ---- K4: deterministic fixed-order final reduce (1 block, 1024 partials) ----
__global__ void k_out(const float* __restrict__ part, float* __restrict__ out,
                      int N, int nblk) {
    __shared__ float red[8];
    int tid = threadIdx.x, lane = tid & 63, wv = tid >> 6;
    float v = 0.f;
    if (tid < nblk)       v += part[tid];
    if (tid + 512 < nblk) v += part[tid + 512];
    v += __shfl_xor(v, 32); v += __shfl_xor(v, 16); v += __shfl_xor(v, 8);
    v += __shfl_xor(v, 4);  v += __shfl_xor(v, 2);  v += __shfl_xor(v, 1);
    if (lane == 0) red[wv] = v;
    __syncthreads();
    if (tid == 0)
        out[0] = -(((red[0] + red[1]) + (red[2] + red[3]))
                 + ((red[4] + red[5]) + (red[6] + red[7]))) / (float)N;
}

extern "C" void kernel_launch(void* const* d_in, const int* in_sizes, int n_in,
                              void* d_out, int out_size, void* d_ws, size_t ws_size,
                              hipStream_t stream) {
    const float* x    = (const float*)d_in[0];   // [N, D]
    const float* kw   = (const float*)d_in[1];   // [C]
    const float* p_in = (const float*)d_in[2];   // [C, D]
    const int*   tgt  = (const int*)d_in[3];     // [N]
    int C = in_sizes[1];
    int N = in_sizes[3];
    float dval = (float)(in_sizes[2] / C);       // == 32
    int nblk = N / SSM;                           // 1024 score blocks

    // ws layout: cnt | list2d | xnb | qb | w | part  (all 64B-aligned sizes)
    int* cnt    = (int*)d_ws;                               // C ints (zeroed)
    int* list2d = cnt + C;                                  // C*CAP ints
    unsigned short* xnb = (unsigned short*)(list2d + (size_t)C * CAP);  // N*D bf16
    unsigned short* qb  = xnb + (size_t)N * D;              // C*D bf16
    float* w    = (float*)(qb + (size_t)C * D);             // C f32
    float* part = w + C;                                    // nblk f32
    (void)n_in; (void)out_size; (void)ws_size;

    // node 1: zero cnt (every replay)
    hipMemsetAsync(cnt, 0, (size_t)C * sizeof(int), stream);
    // node 2: normalize -> bf16 + bucket scatter
    k_norm<<<(N * 8) / 256, 256, 0, stream>>>(x, tgt, xnb, cnt, list2d, N);
    // node 3: per-lane register-resident EMA chains -> qb, w
    k_chain<<<C / 64, 64, 0, stream>>>(xnb, tgt, list2d, cnt, p_in, kw, qb, w, N, C, dval);
    // node 4: full-row score + NLL partials
    k_score<<<nblk, SBT, 0, stream>>>(x, tgt, qb, w, part, N, C);
    // node 5: final reduce
    k_out<<<1, 512, 0, stream>>>(part, (float*)d_out, N, nblk);
}

// Round 14
// 42.808 us; speedup vs baseline: 1.3465x; 1.1959x over previous
//
#include <hip/hip_runtime.h>
#include <hip/hip_bf16.h>
#include <math.h>

#define D 32
#define CAP 28      // Gram-path capacity (P(Poisson(8)>28) ~ 1e-9/class); exact fallback beyond
#define CPB 4       // classes per block (one wave each)
#define SBT 512     // k_score threads (8 waves)
#define SSM 16      // samples per k_score block

typedef __attribute__((ext_vector_type(8))) short short8v;
typedef __attribute__((ext_vector_type(4))) float float4v;

static __device__ __forceinline__ unsigned short f2bf(float f) {
    union { __hip_bfloat16 h; unsigned short u; } cv;
    cv.h = __float2bfloat16(f);
    return cv.u;
}

// ---- K1: bucket + sort + stage + Gram + scalar coefficient recurrence ----
// 512 blocks x 256 threads; wave wv owns class b*4+wv.
// EMA chain u<-(a s + b u)/||.|| reformulated in basis {P, s_0..s_{n-1}}:
// serial part = scalar recurrence (no loads/shuffles on critical path).
__global__ void __launch_bounds__(64 * CPB)
k_solve(const float* __restrict__ x, const int* __restrict__ tgt,
        const float* __restrict__ p_in, const float* __restrict__ kw,
        unsigned short* __restrict__ qb, float* __restrict__ w,
        int N, int C, float dval) {
    __shared__ int   lcnt[CPB];
    __shared__ int   llist[CPB][CAP];
    __shared__ float R[CPB][29][33];     // rows 0..27 = sorted unit samples; row 28 = raw P
    __shared__ float G[CPB][28][28];     // G[k][j] = <s_k, s_j>, j<k
    __shared__ float gP[CPB][29];        // gP[k] = <s_k, P>; gP[28] = <P,P>
    int tid = threadIdx.x, b = blockIdx.x;
    int lane = tid & 63, wv = tid >> 6;
    int c = b * CPB + wv;
    int e = lane & 31;

    // ---- Phase A: block-local bucket of its 4 classes (LDS atomics) ----
    if (tid < CPB) lcnt[tid] = 0;
    __syncthreads();
    for (int i = tid; i < N; i += 64 * CPB) {
        int r = tgt[i] - b * CPB;
        if ((unsigned)r < (unsigned)CPB) {
            int pos = atomicAdd(&lcnt[r], 1);
            if (pos < CAP) llist[r][pos] = i;
        }
    }
    __syncthreads();

    int n = lcnt[wv];
    float kap = fmaxf(kw[c], 0.0f);

    if (n <= CAP) {
        // ---- Phase B: rank-sort indices, stage P + normalized rows ----
        int idx = (lane < n) ? llist[wv][lane] : 0x7fffffff;
        int rank = 0;
        for (int j = 0; j < n; ++j) { int v = __shfl(idx, j); rank += (v < idx) ? 1 : 0; }
        int sorted = idx;
        for (int j = 0; j < n; ++j) {
            int v = __shfl(idx, j); int r = __shfl(rank, j);
            if (r == lane) sorted = v;
        }
        if (lane < D) R[wv][28][e] = p_in[(size_t)c * D + e];   // raw P
        int half = lane >> 5;                  // two rows per iteration
        for (int r0 = 0; r0 < n; r0 += 2) {
            int r = r0 + half;
            int ok = (r < n);
            int si = __shfl(sorted, ok ? r : 0);
            float v = ok ? x[(size_t)si * D + e] : 0.f;
            float ss = v * v;                   // reduce within 32-lane half
            ss += __shfl_xor(ss, 16); ss += __shfl_xor(ss, 8); ss += __shfl_xor(ss, 4);
            ss += __shfl_xor(ss, 2);  ss += __shfl_xor(ss, 1);
            if (ok) R[wv][r][e] = v / fmaxf(sqrtf(ss), 1e-12f);   // eps 1e-12 (F.normalize)
        }

        // ---- Phase C: Gram entries, lane-parallel ----
        int T = n * (n - 1) / 2;
        for (int q = lane; q < T; q += 64) {
            int k = (int)((1.0f + sqrtf(1.0f + 8.0f * (float)q)) * 0.5f);
            while (k * (k - 1) / 2 > q) --k;
            while ((k + 1) * k / 2 <= q) ++k;
            int j = q - k * (k - 1) / 2;
            float a0 = 0.f, a1 = 0.f, a2 = 0.f, a3 = 0.f;
            for (int d4 = 0; d4 < D; d4 += 4) {
                a0 = fmaf(R[wv][k][d4],     R[wv][j][d4],     a0);
                a1 = fmaf(R[wv][k][d4 + 1], R[wv][j][d4 + 1], a1);
                a2 = fmaf(R[wv][k][d4 + 2], R[wv][j][d4 + 2], a2);
                a3 = fmaf(R[wv][k][d4 + 3], R[wv][j][d4 + 3], a3);
            }
            G[wv][k][j] = (a0 + a1) + (a2 + a3);
        }
        for (int k = lane; k <= n; k += 64) {    // lane n writes <P,P>
            int kk = (k < n) ? k : 28;
            float a0 = 0.f, a1 = 0.f, a2 = 0.f, a3 = 0.f;
            for (int d4 = 0; d4 < D; d4 += 4) {
                a0 = fmaf(R[wv][kk][d4],     R[wv][28][d4],     a0);
                a1 = fmaf(R[wv][kk][d4 + 1], R[wv][28][d4 + 1], a1);
                a2 = fmaf(R[wv][kk][d4 + 2], R[wv][28][d4 + 2], a2);
                a3 = fmaf(R[wv][kk][d4 + 3], R[wv][28][d4 + 3], a3);
            }
            gP[wv][(k < n) ? k : 28] = (a0 + a1) + (a2 + a3);
        }

        // ---- Phase D: serial scalar recurrence (replicated on all lanes) ----
        // u_{k+1} = (0.05 s_k + 0.95 u_k)/max(m,1e-12), m^2 = .0025 + .9025*U2 + .095*<s_k,u_k>
        float cc[CAP];
        float cp = 1.0f, U2 = gP[wv][28];
#pragma unroll
        for (int kk = 0; kk < CAP; ++kk) {
            if (kk < n) {
                float dsum = cp * gP[wv][kk];
#pragma unroll
                for (int j = 0; j < CAP; ++j)
                    if (j < kk) dsum = fmaf(cc[j], G[wv][kk][j], dsum);
                float m2 = 0.0025f + fmaf(0.9025f, U2, 0.095f * dsum);
                float m = fmaxf(sqrtf(m2), 1e-12f);
                float binv = 0.95f / m;
                cp *= binv;
#pragma unroll
                for (int j = 0; j < CAP; ++j)
                    if (j < kk) cc[j] *= binv;
                cc[kk] = 0.05f / m;
                U2 = 1.0f;
            }
        }

        // ---- Phase E: recombine u = cp*P + sum c_j s_j, cosine-norm (eps 1e-8) ----
        float u = cp * R[wv][28][e];
#pragma unroll
        for (int j = 0; j < CAP; ++j)
            if (j < n) u = fmaf(cc[j], R[wv][j][e], u);
        float ss = u * u;
        ss += __shfl_xor(ss, 16); ss += __shfl_xor(ss, 8); ss += __shfl_xor(ss, 4);
        ss += __shfl_xor(ss, 2);  ss += __shfl_xor(ss, 1);
        float pninv = 1.0f / fmaxf(sqrtf(ss), 1e-8f);
        if (lane < D) qb[(size_t)c * D + e] = f2bf(kap * pninv * u);
    } else {
        // ---- exact fallback (statistically never): ordered ballot-scan chain ----
        float p = p_in[(size_t)c * D + e];
        for (int ii = 0; ii < N; ii += 64) {
            unsigned long long mb = __ballot(tgt[ii + lane] == c);
            while (mb) {
                int j = __ffsll(mb) - 1;
                mb &= (mb - 1);
                float v = x[(size_t)(ii + j) * D + e];
                float s2 = v * v;
                s2 += __shfl_xor(s2, 16); s2 += __shfl_xor(s2, 8); s2 += __shfl_xor(s2, 4);
                s2 += __shfl_xor(s2, 2);  s2 += __shfl_xor(s2, 1);
                float s = v / fmaxf(sqrtf(s2), 1e-12f);
                p = fmaf(0.05f, s, 0.95f * p);
                float pp = p * p;
                pp += __shfl_xor(pp, 16); pp += __shfl_xor(pp, 8); pp += __shfl_xor(pp, 4);
                pp += __shfl_xor(pp, 2);  pp += __shfl_xor(pp, 1);
                p = p / fmaxf(sqrtf(pp), 1e-12f);
            }
        }
        float pp = p * p;
        pp += __shfl_xor(pp, 16); pp += __shfl_xor(pp, 8); pp += __shfl_xor(pp, 4);
        pp += __shfl_xor(pp, 2);  pp += __shfl_xor(pp, 1);
        float pn = p / fmaxf(sqrtf(pp), 1e-8f);
        if (lane < D) qb[(size_t)c * D + e] = f2bf(kap * pn);
    }

    if (lane == 0) {
        // log C_d(kap), cancellation-free rearrangement
        float nu = 0.5f * dval - 1.0f;
        float z  = kap / nu, z2 = z * z;
        float sq = sqrtf(1.0f + z2);
        float t  = 1.0f / sq;
        float u1 = (3.0f * t - 5.0f * t * t * t) * (1.0f / 24.0f);
        float lw = dval * (-0.918938533204672742f)
                 + nu * (logf(nu) + log1pf(sq) - sq)
                 + 0.5f * logf(6.2831853071795864f * nu)
                 + 0.25f * log1pf(z2)
                 - log1pf(u1 / nu);
        w[c] = __expf(lw);
    }
}

// ---- K2: per-block full-row MFMA + exp rowsum + target-logit capture + NLL ----
// (unchanged, verified) 1024 blocks x 8 waves; block owns 16 samples.
__global__ void __launch_bounds__(SBT)
k_score(const float* __restrict__ x, const int* __restrict__ tgt,
        const unsigned short* __restrict__ qb, const float* __restrict__ w,
        float* __restrict__ part, int N, int C) {
    __shared__ float Sl[8][SSM];
    __shared__ float Lt[SSM];
    int tid = threadIdx.x, b = blockIdx.x;
    int lane = tid & 63, wv = tid >> 6;
    int m = lane & 15, kg = lane >> 4, k0 = kg * 8;
    int s0 = b * SSM;

    short8v a0;
    {
        const float4* px = (const float4*)(x + (size_t)(s0 + m) * D + k0);
        float4 u0 = px[0], u1 = px[1];
        float ss = u0.x*u0.x + u0.y*u0.y + u0.z*u0.z + u0.w*u0.w
                 + u1.x*u1.x + u1.y*u1.y + u1.z*u1.z + u1.w*u1.w;
        ss += __shfl_xor(ss, 16); ss += __shfl_xor(ss, 32);
        float inv = 1.0f / fmaxf(sqrtf(ss), 1e-8f);
        a0[0] = (short)f2bf(u0.x*inv); a0[1] = (short)f2bf(u0.y*inv);
        a0[2] = (short)f2bf(u0.z*inv); a0[3] = (short)f2bf(u0.w*inv);
        a0[4] = (short)f2bf(u1.x*inv); a0[5] = (short)f2bf(u1.y*inv);
        a0[6] = (short)f2bf(u1.z*inv); a0[7] = (short)f2bf(u1.w*inv);
    }

    int tr0[4];
#pragma unroll
    for (int r = 0; r < 4; ++r) tr0[r] = tgt[s0 + kg * 4 + r];

    float4v z = {0.f, 0.f, 0.f, 0.f};
    float4v sa0 = z;
    int ntiles = C >> 7;
    for (int jt = 0; jt < ntiles; ++jt) {
        int c0 = (wv * ntiles + jt) * 16;
        short8v bfrag = *(const short8v*)(qb + (size_t)(c0 + m) * D + k0);
        float wl = w[c0 + m];
        float4v acc0 = __builtin_amdgcn_mfma_f32_16x16x32_bf16(a0, bfrag, z, 0, 0, 0);
#pragma unroll
        for (int r = 0; r < 4; ++r) {
            if (c0 + m == tr0[r]) Lt[kg * 4 + r] = acc0[r];
            sa0[r] = fmaf(wl, __expf(acc0[r]), sa0[r]);
        }
    }
#pragma unroll
    for (int off = 1; off < 16; off <<= 1) {
#pragma unroll
        for (int r = 0; r < 4; ++r) sa0[r] += __shfl_xor(sa0[r], off);
    }
    if (m == 0) {
#pragma unroll
        for (int r = 0; r < 4; ++r) Sl[wv][kg * 4 + r] = sa0[r];
    }
    __syncthreads();

    if (wv == 0) {
        float val = 0.f;
        if (lane < SSM) {
            int s = lane;
            float S = ((Sl[0][s] + Sl[1][s]) + (Sl[2][s] + Sl[3][s]))
                    + ((Sl[4][s] + Sl[5][s]) + (Sl[6][s] + Sl[7][s]));
            int t = tgt[s0 + s];
            val = logf(w[t] * __expf(Lt[s]) / S + 1e-6f);
        }
        val += __shfl_xor(val, 32); val += __shfl_xor(val, 16); val += __shfl_xor(val, 8);
        val += __shfl_xor(val, 4);  val += __shfl_xor(val, 2);  val += __shfl_xor(val, 1);
        if (lane == 0) part[b] = val;
    }
}

// ---- K3: deterministic fixed-order final reduce (1 block, 1024 partials) ----
__global__ void k_out(const float* __restrict__ part, float* __restrict__ out,
                      int N, int nblk) {
    __shared__ float red[8];
    int tid = threadIdx.x, lane = tid & 63, wv = tid >> 6;
    float v = 0.f;
    if (tid < nblk)       v += part[tid];
    if (tid + 512 < nblk) v += part[tid + 512];
    v += __shfl_xor(v, 32); v += __shfl_xor(v, 16); v += __shfl_xor(v, 8);
    v += __shfl_xor(v, 4);  v += __shfl_xor(v, 2);  v += __shfl_xor(v, 1);
    if (lane == 0) red[wv] = v;
    __syncthreads();
    if (tid == 0)
        out[0] = -(((red[0] + red[1]) + (red[2] + red[3]))
                 + ((red[4] + red[5]) + (red[6] + red[7]))) / (float)N;
}

extern "C" void kernel_launch(void* const* d_in, const int* in_sizes, int n_in,
                              void* d_out, int out_size, void* d_ws, size_t ws_size,
                              hipStream_t stream) {
    const float* x    = (const float*)d_in[0];   // [N, D]
    const float* kw   = (const float*)d_in[1];   // [C]
    const float* p_in = (const float*)d_in[2];   // [C, D]
    const int*   tgt  = (const int*)d_in[3];     // [N]
    int C = in_sizes[1];
    int N = in_sizes[3];
    float dval = (float)(in_sizes[2] / C);       // == 32
    int nblk = N / SSM;                           // 1024 score blocks

    // ws layout: qb | w | part
    unsigned short* qb = (unsigned short*)d_ws;            // C*D bf16
    float* w    = (float*)(qb + (size_t)C * D);            // C f32
    float* part = w + C;                                   // nblk f32
    (void)n_in; (void)out_size; (void)ws_size;

    // node 1: bucket + Gram-reformulated EMA chains -> qb, w
    k_solve<<<C / CPB, 64 * CPB, 0, stream>>>(x, tgt, p_in, kw, qb, w, N, C, dval);
    // node 2: full-row score + NLL partials
    k_score<<<nblk, SBT, 0, stream>>>(x, tgt, qb, w, part, N, C);
    // node 3: final reduce
    k_out<<<1, 512, 0, stream>>>(part, (float*)d_out, N, nblk);
}

// Round 15
// 39.156 us; speedup vs baseline: 1.4721x; 1.0933x over previous
//
#include <hip/hip_runtime.h>
#include <hip/hip_bf16.h>
#include <math.h>

#define D 32
#define CAP 28      // Gram-path capacity (P(Poisson(8)>28)~1e-9/class); exact fallback beyond
#define CPB 4       // classes (=waves) per block
#define SBT 512     // k_score threads (8 waves)
#define SSM 16      // samples per k_score block

typedef __attribute__((ext_vector_type(8))) short short8v;
typedef __attribute__((ext_vector_type(4))) float float4v;

static __device__ __forceinline__ unsigned short f2bf(float f) {
    union { __hip_bfloat16 h; unsigned short u; } cv;
    cv.h = __float2bfloat16(f);
    return cv.u;
}
static __device__ __forceinline__ short8v cvt8(float4 u0, float4 u1) {
    short8v o;
    o[0] = (short)f2bf(u0.x); o[1] = (short)f2bf(u0.y);
    o[2] = (short)f2bf(u0.z); o[3] = (short)f2bf(u0.w);
    o[4] = (short)f2bf(u1.x); o[5] = (short)f2bf(u1.y);
    o[6] = (short)f2bf(u1.z); o[7] = (short)f2bf(u1.w);
    return o;
}

// ---- K1: bucket + MFMA Gram + scalar recurrence -> qb (kappa folded), w ----
// 512 blocks x 4 waves; wave owns one class. Rows {s_0..s_{n-1}, 0.., P} Gram'd
// by 4 MFMAs (A==B fragment trick, layout HW-verified by k_score); sample norms
// come from the Gram diagonal (invv), folded into the recurrence coefficients.
__global__ void __launch_bounds__(64 * CPB)
k_gram(const float* __restrict__ x, const int* __restrict__ tgt,
       const float* __restrict__ p_in, const float* __restrict__ kw,
       unsigned short* __restrict__ qb, float* __restrict__ w,
       int N, int C, float dval) {
    __shared__ int   lcnt[CPB];
    __shared__ int   llist[CPB][CAP];
    __shared__ int   slist[CPB][CAP];
    __shared__ float Graw[CPB][32][33];   // raw-row Gram; row 31 = P
    __shared__ float invv[CPB][32];       // 1/max(||r_i||,1e-12)
    int tid = threadIdx.x, b = blockIdx.x;
    int lane = tid & 63, wv = tid >> 6;
    int c = b * CPB + wv, e = lane & 31;

    // ---- Phase A: block-local bucket of its 4 classes (LDS atomics) ----
    if (tid < CPB) lcnt[tid] = 0;
    __syncthreads();
    for (int i = tid; i < N; i += 64 * CPB) {
        int r = tgt[i] - b * CPB;
        if ((unsigned)r < (unsigned)CPB) {
            int pos = atomicAdd(&lcnt[r], 1);
            if (pos < CAP) llist[r][pos] = i;
        }
    }
    __syncthreads();

    int n = lcnt[wv];
    float kap = fmaxf(kw[c], 0.0f);

    if (n <= CAP) {
        // ---- rank-sort indices (ascending) into slist via LDS scatter ----
        int idx = (lane < n) ? llist[wv][lane] : 0x7fffffff;
        int rank = 0;
        for (int j = 0; j < n; ++j) { int v = __shfl(idx, j); rank += (v < idx) ? 1 : 0; }
        if (lane < n) slist[wv][rank] = idx;

        // ---- parallel fragment gather: rows 0..n-1 = raw samples, 31 = raw P ----
        int m = lane & 15, kg = lane >> 4, k0 = kg * 8;
        short8v A0 = {0,0,0,0,0,0,0,0}, A1 = {0,0,0,0,0,0,0,0};
        if (m < n) {
            const float4* px = (const float4*)(x + (size_t)slist[wv][m] * D + k0);
            A0 = cvt8(px[0], px[1]);
        }
        {
            int r = 16 + m;
            if (r < n) {
                const float4* px = (const float4*)(x + (size_t)slist[wv][r] * D + k0);
                A1 = cvt8(px[0], px[1]);
            } else if (r == 31) {
                const float4* px = (const float4*)(p_in + (size_t)c * D + k0);
                A1 = cvt8(px[0], px[1]);
            }
        }

        // ---- Gram via 4 MFMAs (same fragment as both A and B operands) ----
        float4v z = {0.f, 0.f, 0.f, 0.f};
        float4v g00 = __builtin_amdgcn_mfma_f32_16x16x32_bf16(A0, A0, z, 0, 0, 0);
        float4v g01 = __builtin_amdgcn_mfma_f32_16x16x32_bf16(A0, A1, z, 0, 0, 0);
        float4v g10 = __builtin_amdgcn_mfma_f32_16x16x32_bf16(A1, A0, z, 0, 0, 0);
        float4v g11 = __builtin_amdgcn_mfma_f32_16x16x32_bf16(A1, A1, z, 0, 0, 0);
#pragma unroll
        for (int r = 0; r < 4; ++r) {          // C/D: row=(lane>>4)*4+r, col=lane&15
            int rr = kg * 4 + r;
            Graw[wv][rr][m]           = g00[r];
            Graw[wv][rr][16 + m]      = g01[r];
            Graw[wv][16 + rr][m]      = g10[r];
            Graw[wv][16 + rr][16 + m] = g11[r];
        }
        if (lane < 32)
            invv[wv][lane] = 1.0f / fmaxf(sqrtf(Graw[wv][lane][lane]), 1e-12f);

        // ---- Phase D: serial scalar recurrence (replicated; LDS broadcast reads) ----
        // u_{k+1} = (.05 s_k + .95 u_k)/max(m,1e-12);
        // <s_k,u_k> = invv_k * (cp*Graw[k][31] + sum_j cc[j]*Graw[k][j])  (cc has invv folded)
        float cc[CAP];
        float cp = 1.0f, U2 = Graw[wv][31][31];
#pragma unroll
        for (int kk = 0; kk < CAP; ++kk) {
            if (kk < n) {
                float acc = cp * Graw[wv][kk][31];
#pragma unroll
                for (int j = 0; j < CAP; ++j)
                    if (j < kk) acc = fmaf(cc[j], Graw[wv][kk][j], acc);
                float dsum = invv[wv][kk] * acc;
                float m2 = 0.0025f + fmaf(0.9025f, U2, 0.095f * dsum);
                float mm = fmaxf(sqrtf(m2), 1e-12f);
                float binv = 0.95f / mm;
                cp *= binv;
#pragma unroll
                for (int j = 0; j < CAP; ++j)
                    if (j < kk) cc[j] *= binv;
                cc[kk] = 0.05f * invv[wv][kk] / mm;
                U2 = 1.0f;
            }
        }

        // ---- Phase E: recombine u = cp*P + sum cc_j * r_j, cosine-norm (eps 1e-8) ----
        float u = cp * p_in[(size_t)c * D + e];
#pragma unroll
        for (int j = 0; j < CAP; ++j)
            if (j < n) u = fmaf(cc[j], x[(size_t)slist[wv][j] * D + e], u);
        float ss = u * u;
        ss += __shfl_xor(ss, 16); ss += __shfl_xor(ss, 8); ss += __shfl_xor(ss, 4);
        ss += __shfl_xor(ss, 2);  ss += __shfl_xor(ss, 1);
        float pninv = 1.0f / fmaxf(sqrtf(ss), 1e-8f);
        if (lane < D) qb[(size_t)c * D + e] = f2bf(kap * pninv * u);
    } else {
        // ---- exact fallback (statistically never): ordered ballot-scan chain ----
        float p = p_in[(size_t)c * D + e];
        for (int ii = 0; ii < N; ii += 64) {
            unsigned long long mb = __ballot(tgt[ii + lane] == c);
            while (mb) {
                int j = __ffsll(mb) - 1;
                mb &= (mb - 1);
                float v = x[(size_t)(ii + j) * D + e];
                float s2 = v * v;
                s2 += __shfl_xor(s2, 16); s2 += __shfl_xor(s2, 8); s2 += __shfl_xor(s2, 4);
                s2 += __shfl_xor(s2, 2);  s2 += __shfl_xor(s2, 1);
                float s = v / fmaxf(sqrtf(s2), 1e-12f);
                p = fmaf(0.05f, s, 0.95f * p);
                float pp = p * p;
                pp += __shfl_xor(pp, 16); pp += __shfl_xor(pp, 8); pp += __shfl_xor(pp, 4);
                pp += __shfl_xor(pp, 2);  pp += __shfl_xor(pp, 1);
                p = p / fmaxf(sqrtf(pp), 1e-12f);
            }
        }
        float pp = p * p;
        pp += __shfl_xor(pp, 16); pp += __shfl_xor(pp, 8); pp += __shfl_xor(pp, 4);
        pp += __shfl_xor(pp, 2);  pp += __shfl_xor(pp, 1);
        float pn = p / fmaxf(sqrtf(pp), 1e-8f);
        if (lane < D) qb[(size_t)c * D + e] = f2bf(kap * pn);
    }

    if (lane == 0) {
        // log C_d(kap), cancellation-free rearrangement
        float nu = 0.5f * dval - 1.0f;
        float zz = kap / nu, z2 = zz * zz;
        float sq = sqrtf(1.0f + z2);
        float t  = 1.0f / sq;
        float u1 = (3.0f * t - 5.0f * t * t * t) * (1.0f / 24.0f);
        float lw = dval * (-0.918938533204672742f)
                 + nu * (logf(nu) + log1pf(sq) - sq)
                 + 0.5f * logf(6.2831853071795864f * nu)
                 + 0.25f * log1pf(z2)
                 - log1pf(u1 / nu);
        w[c] = __expf(lw);
    }
}

// ---- K2: per-block full-row MFMA + exp rowsum + target-logit capture + NLL ----
// (unchanged, verified) 1024 blocks x 8 waves; block owns 16 samples.
__global__ void __launch_bounds__(SBT)
k_score(const float* __restrict__ x, const int* __restrict__ tgt,
        const unsigned short* __restrict__ qb, const float* __restrict__ w,
        float* __restrict__ part, int N, int C) {
    __shared__ float Sl[8][SSM];
    __shared__ float Lt[SSM];
    int tid = threadIdx.x, b = blockIdx.x;
    int lane = tid & 63, wv = tid >> 6;
    int m = lane & 15, kg = lane >> 4, k0 = kg * 8;
    int s0 = b * SSM;

    short8v a0;
    {
        const float4* px = (const float4*)(x + (size_t)(s0 + m) * D + k0);
        float4 u0 = px[0], u1 = px[1];
        float ss = u0.x*u0.x + u0.y*u0.y + u0.z*u0.z + u0.w*u0.w
                 + u1.x*u1.x + u1.y*u1.y + u1.z*u1.z + u1.w*u1.w;
        ss += __shfl_xor(ss, 16); ss += __shfl_xor(ss, 32);
        float inv = 1.0f / fmaxf(sqrtf(ss), 1e-8f);
        float4 v0, v1;
        v0.x = u0.x*inv; v0.y = u0.y*inv; v0.z = u0.z*inv; v0.w = u0.w*inv;
        v1.x = u1.x*inv; v1.y = u1.y*inv; v1.z = u1.z*inv; v1.w = u1.w*inv;
        a0 = cvt8(v0, v1);
    }

    int tr0[4];
#pragma unroll
    for (int r = 0; r < 4; ++r) tr0[r] = tgt[s0 + kg * 4 + r];

    float4v z = {0.f, 0.f, 0.f, 0.f};
    float4v sa0 = z;
    int ntiles = C >> 7;
    for (int jt = 0; jt < ntiles; ++jt) {
        int c0 = (wv * ntiles + jt) * 16;
        short8v bfrag = *(const short8v*)(qb + (size_t)(c0 + m) * D + k0);
        float wl = w[c0 + m];
        float4v acc0 = __builtin_amdgcn_mfma_f32_16x16x32_bf16(a0, bfrag, z, 0, 0, 0);
#pragma unroll
        for (int r = 0; r < 4; ++r) {
            if (c0 + m == tr0[r]) Lt[kg * 4 + r] = acc0[r];
            sa0[r] = fmaf(wl, __expf(acc0[r]), sa0[r]);
        }
    }
#pragma unroll
    for (int off = 1; off < 16; off <<= 1) {
#pragma unroll
        for (int r = 0; r < 4; ++r) sa0[r] += __shfl_xor(sa0[r], off);
    }
    if (m == 0) {
#pragma unroll
        for (int r = 0; r < 4; ++r) Sl[wv][kg * 4 + r] = sa0[r];
    }
    __syncthreads();

    if (wv == 0) {
        float val = 0.f;
        if (lane < SSM) {
            int s = lane;
            float S = ((Sl[0][s] + Sl[1][s]) + (Sl[2][s] + Sl[3][s]))
                    + ((Sl[4][s] + Sl[5][s]) + (Sl[6][s] + Sl[7][s]));
            int t = tgt[s0 + s];
            val = logf(w[t] * __expf(Lt[s]) / S + 1e-6f);
        }
        val += __shfl_xor(val, 32); val += __shfl_xor(val, 16); val += __shfl_xor(val, 8);
        val += __shfl_xor(val, 4);  val += __shfl_xor(val, 2);  val += __shfl_xor(val, 1);
        if (lane == 0) part[b] = val;
    }
}

// ---- K3: deterministic fixed-order final reduce (1 block, 1024 partials) ----
__global__ void k_out(const float* __restrict__ part, float* __restrict__ out,
                      int N, int nblk) {
    __shared__ float red[8];
    int tid = threadIdx.x, lane = tid & 63, wv = tid >> 6;
    float v = 0.f;
    if (tid < nblk)       v += part[tid];
    if (tid + 512 < nblk) v += part[tid + 512];
    v += __shfl_xor(v, 32); v += __shfl_xor(v, 16); v += __shfl_xor(v, 8);
    v += __shfl_xor(v, 4);  v += __shfl_xor(v, 2);  v += __shfl_xor(v, 1);
    if (lane == 0) red[wv] = v;
    __syncthreads();
    if (tid == 0)
        out[0] = -(((red[0] + red[1]) + (red[2] + red[3]))
                 + ((red[4] + red[5]) + (red[6] + red[7]))) / (float)N;
}

extern "C" void kernel_launch(void* const* d_in, const int* in_sizes, int n_in,
                              void* d_out, int out_size, void* d_ws, size_t ws_size,
                              hipStream_t stream) {
    const float* x    = (const float*)d_in[0];   // [N, D]
    const float* kw   = (const float*)d_in[1];   // [C]
    const float* p_in = (const float*)d_in[2];   // [C, D]
    const int*   tgt  = (const int*)d_in[3];     // [N]
    int C = in_sizes[1];
    int N = in_sizes[3];
    float dval = (float)(in_sizes[2] / C);       // == 32
    int nblk = N / SSM;                           // 1024 score blocks

    // ws layout: qb | w | part
    unsigned short* qb = (unsigned short*)d_ws;            // C*D bf16
    float* w    = (float*)(qb + (size_t)C * D);            // C f32
    float* part = w + C;                                   // nblk f32
    (void)n_in; (void)out_size; (void)ws_size;

    // node 1: bucket + MFMA-Gram EMA solve -> qb, w
    k_gram<<<C / CPB, 64 * CPB, 0, stream>>>(x, tgt, p_in, kw, qb, w, N, C, dval);
    // node 2: full-row score + NLL partials
    k_score<<<nblk, SBT, 0, stream>>>(x, tgt, qb, w, part, N, C);
    // node 3: final reduce
    k_out<<<1, 512, 0, stream>>>(part, (float*)d_out, N, nblk);
}